// Round 18
// baseline (101.144 us; speedup 1.0000x reference)
//
#include <hip/hip_runtime.h>
#include <hip/hip_bf16.h>

// LUTLayerBasic: out[b] = sum_d W[d*16 + ch(b,d)], ch = 4 sign bits of gathered x.
// R18 = R17 + __builtin_amdgcn_sched_barrier(0) after each REFILL.
// Diagnosis: compiler has been SINKING the depth-4 prefetch loads to their
// uses (VGPR evidence: R12=52 vs ~112 expected; R13 depth-8=64 vs ~160;
// R15 no-setprio=40) -> effective depth 1 -> per-step exposed L2/L3 latency
// = the persistent ~60 us gemm. The per-step sched_barrier fences load
// motion across step boundaries so the pipeline actually materializes.
//
// Dims: B=2048, N_IN=2048, D=1024, A=4, O=2048, C=16, K=N_LUT=16384.

typedef __attribute__((ext_vector_type(4))) int i32x4;
typedef __attribute__((ext_vector_type(16))) int i32x16;
typedef __attribute__((ext_vector_type(4))) float f32x4;

__device__ __forceinline__ bool anchors_is_i64(const int* a) {
  int v = 0;
#pragma unroll
  for (int i = 0; i < 32; ++i) v |= a[2 * i + 1];
  return v == 0;
}

__device__ __forceinline__ int ld_anchor(const int* a, int i, bool is64) {
  return is64 ? a[2 * i] : a[i];
}

// ---------------------------------------------------------------------------
// Kernel 0: transpose + bitpack. xbT[n][s] = (x[s][n] > 0) as byte.
// ---------------------------------------------------------------------------
__global__ __launch_bounds__(256) void k_bits(const float* __restrict__ x,
                                              unsigned char* __restrict__ xbT) {
  __shared__ unsigned char t[64][65];
  const int tid = threadIdx.x;
  const int tr = blockIdx.x * 64, tc = blockIdx.y * 64;
  const int c = tid & 63, r0 = tid >> 6;
#pragma unroll
  for (int j = 0; j < 16; ++j) {
    int r = r0 + j * 4;
    t[c][r] = x[(size_t)(tr + r) * 2048 + tc + c] > 0.0f ? 1 : 0;
  }
  __syncthreads();
#pragma unroll
  for (int j = 0; j < 16; ++j) {
    int n = r0 + j * 4;
    xbT[(size_t)(tc + n) * 2048 + tr + c] = t[n][c];
  }
}

// ---------------------------------------------------------------------------
// Kernel 1: channel quads in GEMM-register layout, PRE-SHIFTED (ch<<4).
// For s = g*128 + rf*32 + l: chR[((kq*16+g)*32+l)*4 + rf] has byte di =
// ch(s, 4kq+di) * 16  (LDS LUT byte offset, values 0..240).
// ---------------------------------------------------------------------------
__global__ __launch_bounds__(256) void k_channels3(const unsigned char* __restrict__ xbT,
                                                   const int* __restrict__ anc,
                                                   unsigned* __restrict__ chR) {
  const int s = blockIdx.x * 256 + threadIdx.x;  // gridDim.x = 8
  const int kq = blockIdx.y;                     // [0, 256)
  const bool is64 = anchors_is_i64(anc);
  unsigned word = 0;
#pragma unroll
  for (int di = 0; di < 4; ++di) {
    const int d = kq * 4 + di;
    unsigned ch = 0;
#pragma unroll
    for (int i = 0; i < 4; ++i) {
      int a = ld_anchor(anc, d * 4 + i, is64);
      ch |= (unsigned)xbT[(size_t)a * 2048 + s] << i;
    }
    word |= (ch << 4) << (di * 8);
  }
  const int g = s >> 7, rf = (s >> 5) & 3, l = s & 31;
  chR[(((size_t)kq * 16 + g) * 32 + l) * 4 + rf] = word;
}

// ---------------------------------------------------------------------------
// Kernel 2: W (f32 [16384][2048]) -> i8 fragment-linear chunks:
//   chunk c_idx = (kt*64 + nc)*64 + l  (16 B), byte j:
//   Wq[(2kt + (l>>5))*16 + j][nc*32 + (l&31)],  Wq = round(W*127).
// ---------------------------------------------------------------------------
__global__ __launch_bounds__(256) void k_wfrag_i8(const float* __restrict__ W,
                                                  uint4* __restrict__ wfq) {
  const unsigned flat = blockIdx.x * 256 + threadIdx.x;  // [0, 2097152)
  const unsigned l = flat & 63u, nc = (flat >> 6) & 63u, kt = flat >> 12;
  const unsigned dd = 2u * kt + (l >> 5), col = nc * 32u + (l & 31u);
  const float* base = W + (size_t)(dd * 16u) * 2048u + col;
  unsigned wd[4];
#pragma unroll
  for (int wi = 0; wi < 4; ++wi) {
    unsigned v = 0;
#pragma unroll
    for (int bj = 0; bj < 4; ++bj) {
      float f = base[(size_t)(wi * 4 + bj) * 2048u];
      int q = (int)(f * 127.0f + 0.5f);
      q = q < 0 ? 0 : (q > 127 ? 127 : q);
      v |= (unsigned)q << (bj * 8);
    }
    wd[wi] = v;
  }
  uint4 o;
  o.x = wd[0]; o.y = wd[1]; o.z = wd[2]; o.w = wd[3];
  wfq[flat] = o;
}

// ---------------------------------------------------------------------------
// Kernel 3: streaming i8 GEMM, LDS one-hot LUT for A, FENCED depth-4
// register prefetch. Block 256x32 (4 waves in M), wave 64x32 (rf=2), NB=256
// BK64 steps. Grid 512. KP=1, plain stores.
// ---------------------------------------------------------------------------
__global__ __launch_bounds__(256, 2) void k_gemm(const uint4* __restrict__ wfq,
                                                 const unsigned* __restrict__ chR,
                                                 float* __restrict__ out) {
  constexpr int NB = 256;  // BK64 steps, full K
  __shared__ __align__(16) unsigned lut[16][4];  // entry c: one-hot i8 frag

  const int tid = threadIdx.x, lane = tid & 63;
  const int w = tid >> 6;  // wave index in M within block
  const unsigned q = (unsigned)(lane >> 5), q8 = q << 3;

  // Build LUT: entry e, dword d: byte b set iff d*4+b == e.
  if (tid < 64) {
    int e = tid >> 2, d = tid & 3;
    unsigned v = 0;
    int base = d * 4;
    if (e >= base && e < base + 4) v = 1u << ((e - base) * 8);
    lut[e][d] = v;
  }
  __syncthreads();
  const char* lutb = (const char*)lut;

  // XCD decode (512 = 8 XCD x 64): XCD owns 8 col-strips x all 8 mBlk.
  const unsigned orig = blockIdx.x;
  const unsigned xcd = orig & 7u, slot = orig >> 3;   // slot [0,64)
  const unsigned strip = xcd * 8u + (slot & 7u);      // [0,64) col strip (32 cols)
  const unsigned mBlk = slot >> 3;                    // [0,8) 256-row block

  // W fragment pointer: chunk (kt*64 + nc)*64 + lane, nc = strip, kt = 2*kq.
  // Step stride = 8192 uint4; second K32 half at +4096.
  const uint4* wp0 = wfq + ((size_t)strip * 64u) + lane;
  const uint4* wp1 = wp0 + 4096;
  // Channel pointer: uint2 per (kq, g, lane&31, rf-pair). g = mBlk*2 + (w>>1),
  // rf-pair = w&1. Step stride = 1024 uint2.
  const unsigned g = mBlk * 2u + ((unsigned)w >> 1);
  const uint2* cp = (const uint2*)chR +
                    (((size_t)g) * 32u + (lane & 31)) * 2u + ((unsigned)w & 1u);

  i32x16 acc[2] = {};

#define MFMA_I8(a, b, c) __builtin_amdgcn_mfma_i32_32x32x32_i8((a), (b), (c), 0, 0, 0)

  uint4 b0[4], b1[4];
  uint2 cq[4];
#pragma unroll
  for (int i = 0; i < 4; ++i) {
    b0[i] = wp0[(size_t)i * 8192];
    b1[i] = wp1[(size_t)i * 8192];
    cq[i] = cp[(size_t)i * 1024];
  }

  i32x4 afA[4], afB[4];

  // Load the 4 A-fragments for buffer i's step from the LDS LUT.
#define LOADA(af, i)                                                      \
  {                                                                       \
    unsigned a0 = (cq[i].x >> q8) & 0xFFu;                                \
    unsigned a1 = (cq[i].y >> q8) & 0xFFu;                                \
    unsigned a2 = (cq[i].x >> (16u + q8)) & 0xFFu;                        \
    unsigned a3 = (cq[i].y >> (16u + q8)) & 0xFFu;                        \
    af[0] = *(const i32x4*)(lutb + a0);                                   \
    af[1] = *(const i32x4*)(lutb + a1);                                   \
    af[2] = *(const i32x4*)(lutb + a2);                                   \
    af[3] = *(const i32x4*)(lutb + a3);                                   \
  }

#define COMPUTE(i, af)                                                    \
  {                                                                       \
    const i32x4 vb0 = *(const i32x4*)&b0[i];                              \
    const i32x4 vb1 = *(const i32x4*)&b1[i];                              \
    __builtin_amdgcn_s_setprio(1);                                        \
    acc[0] = MFMA_I8(af[0], vb0, acc[0]);                                 \
    acc[1] = MFMA_I8(af[1], vb0, acc[1]);                                 \
    acc[0] = MFMA_I8(af[2], vb1, acc[0]);                                 \
    acc[1] = MFMA_I8(af[3], vb1, acc[1]);                                 \
    __builtin_amdgcn_s_setprio(0);                                        \
  }
  // Refill buffer i for step p+4 (clamped at tail -> dead reload), then a
  // scheduling fence so the loads cannot sink past this step boundary.
#define REFILL(i, p)                                                      \
  {                                                                       \
    const int np = ((p) + 4 < NB) ? (p) + 4 : (p);                        \
    b0[i] = wp0[(size_t)np * 8192];                                       \
    b1[i] = wp1[(size_t)np * 8192];                                       \
    cq[i] = cp[(size_t)np * 1024];                                        \
  }                                                                       \
  __builtin_amdgcn_sched_barrier(0);

  LOADA(afA, 0)
  for (int p = 0; p < NB; p += 4) {
    LOADA(afB, 1)
    COMPUTE(0, afA) REFILL(0, p)
    LOADA(afA, 2)
    COMPUTE(1, afB) REFILL(1, p + 1)
    LOADA(afB, 3)
    COMPUTE(2, afA) REFILL(2, p + 2)
    LOADA(afA, 0)   // step p+4 (cq[0] refilled above); tail: unused
    COMPUTE(3, afB) REFILL(3, p + 3)
  }
#undef LOADA
#undef COMPUTE
#undef REFILL

  // Epilogue: plain stores. C/D 32x32 layout: col = lane&31,
  // row = (reg&3) + 8*(reg>>2) + 4*q.
  const float scale = 1.0f / 127.0f;
  const int c = (int)strip * 32 + (lane & 31);
  const int rowW = (int)mBlk * 256 + w * 64;  // wave row origin
#pragma unroll
  for (int rf = 0; rf < 2; ++rf) {
    const int r0 = rowW + rf * 32 + (int)(q * 4u);
#pragma unroll
    for (int reg = 0; reg < 16; ++reg) {
      int r = r0 + (reg & 3) + 8 * (reg >> 2);
      out[(size_t)r * 2048 + c] = (float)acc[rf][reg] * scale;
    }
  }
}

// ---------------------------------------------------------------------------
// Fallback (ws too small): direct gather row-sum, one block per sample.
// ---------------------------------------------------------------------------
__global__ __launch_bounds__(256) void k_direct(const float* __restrict__ x,
                                                const int* __restrict__ anc,
                                                const float* __restrict__ W,
                                                float* __restrict__ out) {
  __shared__ unsigned rowoff[1024];
  const int b = blockIdx.x;
  const bool is64 = anchors_is_i64(anc);
  for (int d = threadIdx.x; d < 1024; d += 256) {
    unsigned ch = 0;
#pragma unroll
    for (int i = 0; i < 4; ++i) {
      int a = ld_anchor(anc, d * 4 + i, is64);
      ch |= (x[(size_t)b * 2048 + a] > 0.0f ? 1u : 0u) << i;
    }
    rowoff[d] = (unsigned)(d * 16 + ch) * 2048u;
  }
  __syncthreads();
  f32x4 a0 = {0.f, 0.f, 0.f, 0.f}, a1 = {0.f, 0.f, 0.f, 0.f};
  const int o0 = threadIdx.x * 4, o1 = 1024 + threadIdx.x * 4;
  for (int d = 0; d < 1024; ++d) {
    unsigned ro = rowoff[d];
    a0 += *(const f32x4*)(W + ro + o0);
    a1 += *(const f32x4*)(W + ro + o1);
  }
  *(f32x4*)(out + (size_t)b * 2048 + o0) = a0;
  *(f32x4*)(out + (size_t)b * 2048 + o1) = a1;
}

// ---------------------------------------------------------------------------
extern "C" void kernel_launch(void* const* d_in, const int* in_sizes, int n_in,
                              void* d_out, int out_size, void* d_ws, size_t ws_size,
                              hipStream_t stream) {
  const float* x = (const float*)d_in[0];
  const int* anc = (const int*)d_in[1];
  const float* W = (const float*)d_in[2];
  float* out = (float*)d_out;

  const size_t CHR_BYTES = 2ull * 1024 * 1024;   // chR: 256 x 16 x 32 uint4
  const size_t WFQ_BYTES = 32ull * 1024 * 1024;  // wfq: 2M x 16 B (i8)
  const size_t XBT_BYTES = 4ull * 1024 * 1024;   // xbT: 2048 x 2048 u8
  const size_t BASE = CHR_BYTES + WFQ_BYTES + XBT_BYTES;  // 38 MiB

  if (ws_size < BASE) {
    k_direct<<<2048, 256, 0, stream>>>(x, anc, W, out);
    return;
  }

  unsigned* chR = (unsigned*)d_ws;
  uint4* wfq = (uint4*)((char*)d_ws + CHR_BYTES);
  unsigned char* xbT = (unsigned char*)((char*)d_ws + CHR_BYTES + WFQ_BYTES);

  k_bits<<<dim3(32, 32), 256, 0, stream>>>(x, xbT);
  k_channels3<<<dim3(8, 256), 256, 0, stream>>>(xbT, anc, chR);
  k_wfrag_i8<<<8192, 256, 0, stream>>>(W, wfq);
  k_gemm<<<512, 256, 0, stream>>>(wfq, chR, out);
}

// Round 21
// 100.896 us; speedup vs baseline: 1.0025x; 1.0025x over previous
//
#include <hip/hip_runtime.h>
#include <hip/hip_bf16.h>

// LUTLayerBasic: out[b] = sum_d W[d*16 + ch(b,d)], ch = 4 sign bits of gathered x.
// R21 = R17 verbatim (best passing: 100.8 us total). After R19/R20's
// barrier-pipeline correctness failures (identical absmax 556, cause not
// isolatable without disasm), banking the verified best kernel:
//  - i8 one-hot MFMA streaming GEMM, wave 64x32 (rf=2), block 256x32
//    (4 waves in M), grid 512, KP=1, plain stores, no atomics.
//  - 256 B LDS one-hot LUT for A-fragments (1 ds_read_b128 each, 2-way max
//    bank alias = free); chR pre-shifted (ch<<4) for direct LUT addressing.
//  - depth-4 register prefetch + setprio (R15 ablation showed setprio is
//    load-bearing for keeping the pipeline alive).
//
// Dims: B=2048, N_IN=2048, D=1024, A=4, O=2048, C=16, K=N_LUT=16384.

typedef __attribute__((ext_vector_type(4))) int i32x4;
typedef __attribute__((ext_vector_type(16))) int i32x16;
typedef __attribute__((ext_vector_type(4))) float f32x4;

__device__ __forceinline__ bool anchors_is_i64(const int* a) {
  int v = 0;
#pragma unroll
  for (int i = 0; i < 32; ++i) v |= a[2 * i + 1];
  return v == 0;
}

__device__ __forceinline__ int ld_anchor(const int* a, int i, bool is64) {
  return is64 ? a[2 * i] : a[i];
}

// ---------------------------------------------------------------------------
// Kernel 0: transpose + bitpack. xbT[n][s] = (x[s][n] > 0) as byte.
// ---------------------------------------------------------------------------
__global__ __launch_bounds__(256) void k_bits(const float* __restrict__ x,
                                              unsigned char* __restrict__ xbT) {
  __shared__ unsigned char t[64][65];
  const int tid = threadIdx.x;
  const int tr = blockIdx.x * 64, tc = blockIdx.y * 64;
  const int c = tid & 63, r0 = tid >> 6;
#pragma unroll
  for (int j = 0; j < 16; ++j) {
    int r = r0 + j * 4;
    t[c][r] = x[(size_t)(tr + r) * 2048 + tc + c] > 0.0f ? 1 : 0;
  }
  __syncthreads();
#pragma unroll
  for (int j = 0; j < 16; ++j) {
    int n = r0 + j * 4;
    xbT[(size_t)(tc + n) * 2048 + tr + c] = t[n][c];
  }
}

// ---------------------------------------------------------------------------
// Kernel 1: channel quads in GEMM-register layout, PRE-SHIFTED (ch<<4).
// For s = g*128 + rf*32 + l: chR[((kq*16+g)*32+l)*4 + rf] has byte di =
// ch(s, 4kq+di) * 16  (LDS LUT byte offset, values 0..240).
// ---------------------------------------------------------------------------
__global__ __launch_bounds__(256) void k_channels3(const unsigned char* __restrict__ xbT,
                                                   const int* __restrict__ anc,
                                                   unsigned* __restrict__ chR) {
  const int s = blockIdx.x * 256 + threadIdx.x;  // gridDim.x = 8
  const int kq = blockIdx.y;                     // [0, 256)
  const bool is64 = anchors_is_i64(anc);
  unsigned word = 0;
#pragma unroll
  for (int di = 0; di < 4; ++di) {
    const int d = kq * 4 + di;
    unsigned ch = 0;
#pragma unroll
    for (int i = 0; i < 4; ++i) {
      int a = ld_anchor(anc, d * 4 + i, is64);
      ch |= (unsigned)xbT[(size_t)a * 2048 + s] << i;
    }
    word |= (ch << 4) << (di * 8);
  }
  const int g = s >> 7, rf = (s >> 5) & 3, l = s & 31;
  chR[(((size_t)kq * 16 + g) * 32 + l) * 4 + rf] = word;
}

// ---------------------------------------------------------------------------
// Kernel 2: W (f32 [16384][2048]) -> i8 fragment-linear chunks:
//   chunk c_idx = (kt*64 + nc)*64 + l  (16 B), byte j:
//   Wq[(2kt + (l>>5))*16 + j][nc*32 + (l&31)],  Wq = round(W*127).
// ---------------------------------------------------------------------------
__global__ __launch_bounds__(256) void k_wfrag_i8(const float* __restrict__ W,
                                                  uint4* __restrict__ wfq) {
  const unsigned flat = blockIdx.x * 256 + threadIdx.x;  // [0, 2097152)
  const unsigned l = flat & 63u, nc = (flat >> 6) & 63u, kt = flat >> 12;
  const unsigned dd = 2u * kt + (l >> 5), col = nc * 32u + (l & 31u);
  const float* base = W + (size_t)(dd * 16u) * 2048u + col;
  unsigned wd[4];
#pragma unroll
  for (int wi = 0; wi < 4; ++wi) {
    unsigned v = 0;
#pragma unroll
    for (int bj = 0; bj < 4; ++bj) {
      float f = base[(size_t)(wi * 4 + bj) * 2048u];
      int q = (int)(f * 127.0f + 0.5f);
      q = q < 0 ? 0 : (q > 127 ? 127 : q);
      v |= (unsigned)q << (bj * 8);
    }
    wd[wi] = v;
  }
  uint4 o;
  o.x = wd[0]; o.y = wd[1]; o.z = wd[2]; o.w = wd[3];
  wfq[flat] = o;
}

// ---------------------------------------------------------------------------
// Kernel 3: streaming i8 GEMM, LDS one-hot LUT for A. KP=1, depth-4 register
// prefetch, A-frag 1-step lookahead. Block 256x32 (4 waves in M), wave 64x32
// (rf=2), NB=256 BK64 steps. Grid 512. Plain stores.
// ---------------------------------------------------------------------------
__global__ __launch_bounds__(256, 2) void k_gemm(const uint4* __restrict__ wfq,
                                                 const unsigned* __restrict__ chR,
                                                 float* __restrict__ out) {
  constexpr int NB = 256;  // BK64 steps, full K
  __shared__ __align__(16) unsigned lut[16][4];  // entry c: one-hot i8 frag

  const int tid = threadIdx.x, lane = tid & 63;
  const int w = tid >> 6;  // wave index in M within block
  const unsigned q = (unsigned)(lane >> 5), q8 = q << 3;

  // Build LUT: entry e, dword d: byte b set iff d*4+b == e.
  if (tid < 64) {
    int e = tid >> 2, d = tid & 3;
    unsigned v = 0;
    int base = d * 4;
    if (e >= base && e < base + 4) v = 1u << ((e - base) * 8);
    lut[e][d] = v;
  }
  __syncthreads();
  const char* lutb = (const char*)lut;

  // XCD decode (512 = 8 XCD x 64): XCD owns 8 col-strips x all 8 mBlk.
  const unsigned orig = blockIdx.x;
  const unsigned xcd = orig & 7u, slot = orig >> 3;   // slot [0,64)
  const unsigned strip = xcd * 8u + (slot & 7u);      // [0,64) col strip (32 cols)
  const unsigned mBlk = slot >> 3;                    // [0,8) 256-row block

  // W fragment pointer: chunk (kt*64 + nc)*64 + lane, nc = strip, kt = 2*kq.
  // Step stride = 8192 uint4; second K32 half at +4096.
  const uint4* wp0 = wfq + ((size_t)strip * 64u) + lane;
  const uint4* wp1 = wp0 + 4096;
  // Channel pointer: uint2 per (kq, g, lane&31, rf-pair). g = mBlk*2 + (w>>1),
  // rf-pair = w&1. Step stride = 1024 uint2.
  const unsigned g = mBlk * 2u + ((unsigned)w >> 1);
  const uint2* cp = (const uint2*)chR +
                    (((size_t)g) * 32u + (lane & 31)) * 2u + ((unsigned)w & 1u);

  i32x16 acc[2] = {};

#define MFMA_I8(a, b, c) __builtin_amdgcn_mfma_i32_32x32x32_i8((a), (b), (c), 0, 0, 0)

  uint4 b0[4], b1[4];
  uint2 cq[4];
#pragma unroll
  for (int i = 0; i < 4; ++i) {
    b0[i] = wp0[(size_t)i * 8192];
    b1[i] = wp1[(size_t)i * 8192];
    cq[i] = cp[(size_t)i * 1024];
  }

  i32x4 afA[4], afB[4];

  // Load the 4 A-fragments for buffer i's step from the LDS LUT.
#define LOADA(af, i)                                                      \
  {                                                                       \
    unsigned a0 = (cq[i].x >> q8) & 0xFFu;                                \
    unsigned a1 = (cq[i].y >> q8) & 0xFFu;                                \
    unsigned a2 = (cq[i].x >> (16u + q8)) & 0xFFu;                        \
    unsigned a3 = (cq[i].y >> (16u + q8)) & 0xFFu;                        \
    af[0] = *(const i32x4*)(lutb + a0);                                   \
    af[1] = *(const i32x4*)(lutb + a1);                                   \
    af[2] = *(const i32x4*)(lutb + a2);                                   \
    af[3] = *(const i32x4*)(lutb + a3);                                   \
  }

#define COMPUTE(i, af)                                                    \
  {                                                                       \
    const i32x4 vb0 = *(const i32x4*)&b0[i];                              \
    const i32x4 vb1 = *(const i32x4*)&b1[i];                              \
    __builtin_amdgcn_s_setprio(1);                                        \
    acc[0] = MFMA_I8(af[0], vb0, acc[0]);                                 \
    acc[1] = MFMA_I8(af[1], vb0, acc[1]);                                 \
    acc[0] = MFMA_I8(af[2], vb1, acc[0]);                                 \
    acc[1] = MFMA_I8(af[3], vb1, acc[1]);                                 \
    __builtin_amdgcn_s_setprio(0);                                        \
  }
  // Refill buffer i for step p+4 (clamped at tail -> dead reload).
#define REFILL(i, p)                                                      \
  {                                                                       \
    const int np = ((p) + 4 < NB) ? (p) + 4 : (p);                        \
    b0[i] = wp0[(size_t)np * 8192];                                       \
    b1[i] = wp1[(size_t)np * 8192];                                       \
    cq[i] = cp[(size_t)np * 1024];                                        \
  }

  LOADA(afA, 0)
  for (int p = 0; p < NB; p += 4) {
    LOADA(afB, 1)
    COMPUTE(0, afA) REFILL(0, p)
    LOADA(afA, 2)
    COMPUTE(1, afB) REFILL(1, p + 1)
    LOADA(afB, 3)
    COMPUTE(2, afA) REFILL(2, p + 2)
    LOADA(afA, 0)   // step p+4 (cq[0] refilled above); tail: unused
    COMPUTE(3, afB) REFILL(3, p + 3)
  }
#undef LOADA
#undef COMPUTE
#undef REFILL

  // Epilogue: plain stores. C/D 32x32 layout: col = lane&31,
  // row = (reg&3) + 8*(reg>>2) + 4*q.
  const float scale = 1.0f / 127.0f;
  const int c = (int)strip * 32 + (lane & 31);
  const int rowW = (int)mBlk * 256 + w * 64;  // wave row origin
#pragma unroll
  for (int rf = 0; rf < 2; ++rf) {
    const int r0 = rowW + rf * 32 + (int)(q * 4u);
#pragma unroll
    for (int reg = 0; reg < 16; ++reg) {
      int r = r0 + (reg & 3) + 8 * (reg >> 2);
      out[(size_t)r * 2048 + c] = (float)acc[rf][reg] * scale;
    }
  }
}

// ---------------------------------------------------------------------------
// Fallback (ws too small): direct gather row-sum, one block per sample.
// ---------------------------------------------------------------------------
__global__ __launch_bounds__(256) void k_direct(const float* __restrict__ x,
                                                const int* __restrict__ anc,
                                                const float* __restrict__ W,
                                                float* __restrict__ out) {
  __shared__ unsigned rowoff[1024];
  const int b = blockIdx.x;
  const bool is64 = anchors_is_i64(anc);
  for (int d = threadIdx.x; d < 1024; d += 256) {
    unsigned ch = 0;
#pragma unroll
    for (int i = 0; i < 4; ++i) {
      int a = ld_anchor(anc, d * 4 + i, is64);
      ch |= (x[(size_t)b * 2048 + a] > 0.0f ? 1u : 0u) << i;
    }
    rowoff[d] = (unsigned)(d * 16 + ch) * 2048u;
  }
  __syncthreads();
  f32x4 a0 = {0.f, 0.f, 0.f, 0.f}, a1 = {0.f, 0.f, 0.f, 0.f};
  const int o0 = threadIdx.x * 4, o1 = 1024 + threadIdx.x * 4;
  for (int d = 0; d < 1024; ++d) {
    unsigned ro = rowoff[d];
    a0 += *(const f32x4*)(W + ro + o0);
    a1 += *(const f32x4*)(W + ro + o1);
  }
  *(f32x4*)(out + (size_t)b * 2048 + o0) = a0;
  *(f32x4*)(out + (size_t)b * 2048 + o1) = a1;
}

// ---------------------------------------------------------------------------
extern "C" void kernel_launch(void* const* d_in, const int* in_sizes, int n_in,
                              void* d_out, int out_size, void* d_ws, size_t ws_size,
                              hipStream_t stream) {
  const float* x = (const float*)d_in[0];
  const int* anc = (const int*)d_in[1];
  const float* W = (const float*)d_in[2];
  float* out = (float*)d_out;

  const size_t CHR_BYTES = 2ull * 1024 * 1024;   // chR: 256 x 16 x 32 uint4
  const size_t WFQ_BYTES = 32ull * 1024 * 1024;  // wfq: 2M x 16 B (i8)
  const size_t XBT_BYTES = 4ull * 1024 * 1024;   // xbT: 2048 x 2048 u8
  const size_t BASE = CHR_BYTES + WFQ_BYTES + XBT_BYTES;  // 38 MiB

  if (ws_size < BASE) {
    k_direct<<<2048, 256, 0, stream>>>(x, anc, W, out);
    return;
  }

  unsigned* chR = (unsigned*)d_ws;
  uint4* wfq = (uint4*)((char*)d_ws + CHR_BYTES);
  unsigned char* xbT = (unsigned char*)((char*)d_ws + CHR_BYTES + WFQ_BYTES);

  k_bits<<<dim3(32, 32), 256, 0, stream>>>(x, xbT);
  k_channels3<<<dim3(8, 256), 256, 0, stream>>>(xbT, anc, chR);
  k_wfrag_i8<<<8192, 256, 0, stream>>>(W, wfq);
  k_gemm<<<512, 256, 0, stream>>>(wfq, chR, out);
}